// Round 9
// baseline (126.449 us; speedup 1.0000x reference)
//
#include <hip/hip_runtime.h>
#include <hip/hip_bf16.h>

#define NS     32768
#define NROWS  2048
#define HOP    127
#define NW     257
#define NB     128
#define WT2    32            // windows per tile
#define NT2    9             // ceil(257/32); tile 8 has 1 valid window
#define TWOPI_255 0.02463994236f   // 2*pi/255

typedef _Float16 f16;
typedef __attribute__((ext_vector_type(2))) _Float16 f16x2;
typedef __attribute__((ext_vector_type(8))) _Float16 f16x8;
typedef __attribute__((ext_vector_type(4))) float f32x4;

__device__ inline f32x4 load4u(const char* p) {  // 4B-aligned 16B load
    f32x4 v;
    __builtin_memcpy(&v, p, 16);
    return v;
}

// ---------------------------------------------------------------------------
// Kernel 1: folded-DFT basis table (64 KB), fragment-ordered.
// Fragment fi (0..63): owner-wave layout from round 8 kept verbatim;
// lane l holds f16x8 for comp = (fi>>5)*128 + ((fi>>3)&3)*32 + ((fi>>2)&1)*16
// + (l&15), k = (fi&3)*32 + (l>>4)*8 + j.
// ---------------------------------------------------------------------------
__global__ __launch_bounds__(256)
void basis_kernel(f16* __restrict__ bt) {
    const int t  = blockIdx.x * 256 + threadIdx.x;   // 0..4095
    const int fi = t >> 6;
    const int l  = t & 63;
    const int cq = fi >> 3;
    const int nt = (fi >> 2) & 1;
    const int kk = fi & 3;
    const int is_sin = cq >> 2;
    const int f  = (cq & 3) * 32 + nt * 16 + (l & 15);   // freq 0..127
    int m = (f * (kk * 32 + (l >> 4) * 8)) % 255;
    f16x8 v;
    #pragma unroll
    for (int j = 0; j < 8; ++j) {
        const float ang = (float)m * TWOPI_255;
        v[j] = (f16)(is_sin ? __sinf(ang) : __cosf(ang));
        m += f; if (m >= 255) m -= 255;
    }
    *(f16x8*)(bt + (size_t)t * 8) = v;   // 16B/thread, coalesced
}

// ---------------------------------------------------------------------------
// Kernel 2: one block (8 waves, 512 thr) per row; 32-window M-tiles.
// Wave cq: mg = cq>>2 (window half), hs = (cq>>1)&1 (cos/sin), ng = cq&1
// (comp group of 64). K folded 255->128: y+[k]=x[k]+x[255-k] (cos),
// y-[k]=x[k]-x[255-k] (sin). S[f] = (sum_w Ccos^2 + Csin^2)/257.
// ---------------------------------------------------------------------------
__global__ __launch_bounds__(512, 3)
void psd_kernel(const float* __restrict__ X, const f16* __restrict__ bt,
                float* __restrict__ out) {
    const int row  = blockIdx.x;
    const int tid  = threadIdx.x;
    const int lane = tid & 63;
    const int cq   = tid >> 6;      // wave 0..7
    const int r16  = lane & 15;
    const int kg   = lane >> 4;
    const int mg   = cq >> 2;       // window-half 0/1
    const int hs   = (cq >> 1) & 1; // 0=cos(y+), 1=sin(y-)
    const int ng   = cq & 1;        // comp group of 64

    __shared__ alignas(16) f16 atile[2][WT2 * 256];  // 2 x 16 KB, XOR-swizzled
    __shared__ float scol[2][256];

    const char* __restrict__ xrow = (const char*)(X + (size_t)row * NS);

    const int sw2 = tid >> 4;           // staging window 0..31
    const int sq2 = tid & 15;           // staging k-octet 0..15

    // loop-invariant per-lane global byte offsets (tile-local)
    const uint voff_f = (uint)((sw2 * HOP + sq2 * 8) * 4);
    const uint voff_r = (uint)((sw2 * HOP + 248 - sq2 * 8) * 4);
    const uint vclamp = (uint)((NS - 4) * 4);

    // ---- tile-0 staging loads ----
    f32x4 fva = load4u(xrow + voff_f);
    f32x4 fvb = load4u(xrow + voff_f + 16);
    f32x4 rva = load4u(xrow + voff_r);
    f32x4 rvb = load4u(xrow + voff_r + 16);

    // ---- basis fragments: 16 frags = 64 VGPR (table is L2-resident) ----
    f16x8 bfrag[4][4];
    {
        const char* bp = (const char*)bt + (uint)(lane * 16);
        #pragma unroll
        for (int nt = 0; nt < 4; ++nt) {
            const int fi = (hs * 4 + ng * 2 + (nt >> 1)) * 8 + (nt & 1) * 4;
            #pragma unroll
            for (int kk = 0; kk < 4; ++kk)
                bfrag[nt][kk] = *(const f16x8*)(bp + (uint)((fi + kk) * 1024));
        }
    }

    char* const lds = (char*)&atile[0][0];

    // hoisted LDS byte offsets
    const uint wr_p = ((uint)(sw2 * 512 + sq2 * 16)) ^ ((uint)((sw2 & 7) << 4));
    const uint wr_m = wr_p + 256;                    // +256 doesn't touch swz bits
    const int  arow = mg * 16 + r16;
    uint rd[4];
    #pragma unroll
    for (int kk = 0; kk < 4; ++kk)
        rd[kk] = ((uint)(arow * 512 + hs * 256 + kg * 16 + kk * 64))
               ^ ((uint)((arow & 7) << 4));

    // ---- packed fold (8 pairs) + 2 x ds_write_b128 ----
    auto fold_write = [&](char* wp, bool valid) {
        f16x8 h0, h1;
        #pragma unroll
        for (int q = 0; q < 4; ++q) {
            const int j0 = 2 * q, j1 = 2 * q + 1;
            const float f0 = (j0 < 4) ? fva[j0] : fvb[j0 - 4];
            const float f1 = (j1 < 4) ? fva[j1] : fvb[j1 - 4];
            // partner of k=sq2*8+j is x[b+255-k] = (j<4) ? rvb[3-j] : rva[7-j]
            const float r0 = (j0 < 4) ? rvb[3 - j0] : rva[7 - j0];
            const float r1 = (j1 < 4) ? rvb[3 - j1] : rva[7 - j1];
            const f16x2 fp = __builtin_bit_cast(f16x2, __builtin_amdgcn_cvt_pkrtz(f0, f1));
            const f16x2 rp = __builtin_bit_cast(f16x2, __builtin_amdgcn_cvt_pkrtz(r0, r1));
            const f16x2 s = fp + rp;
            const f16x2 d = fp - rp;
            h0[j0] = s[0]; h0[j1] = s[1];
            h1[j0] = d[0]; h1[j1] = d[1];
        }
        if (sq2 == 0) { h0[0] = (f16)fva[0]; h1[0] = (f16)0.0f; }  // k=0: pad partner
        if (!valid) {
            #pragma unroll
            for (int j = 0; j < 8; ++j) { h0[j] = (f16)0.0f; h1[j] = (f16)0.0f; }
        }
        *(f16x8*)(wp + wr_p) = h0;
        *(f16x8*)(wp + wr_m) = h1;
    };

    // ---- prologue: fold tile 0, issue tile-1 loads ----
    fold_write(lds, true);
    {
        const uint tb = (uint)(WT2 * HOP * 4);
        fva = load4u(xrow + (voff_f + tb));
        fvb = load4u(xrow + (voff_f + tb + 16));
        rva = load4u(xrow + (voff_r + tb));
        rvb = load4u(xrow + (voff_r + tb + 16));
    }
    asm volatile("s_waitcnt lgkmcnt(0)" ::: "memory");
    __builtin_amdgcn_s_barrier();
    asm volatile("" ::: "memory");

    float ssum[4] = {0.f, 0.f, 0.f, 0.f};

    for (int mt = 0; mt < NT2; ++mt) {
        const char* ap = lds + ((mt & 1) << 14);

        f32x4 acc0 = {0,0,0,0}, acc1 = {0,0,0,0}, acc2 = {0,0,0,0}, acc3 = {0,0,0,0};
        __builtin_amdgcn_s_setprio(1);
        #pragma unroll
        for (int kk = 0; kk < 4; ++kk) {
            const f16x8 af = *(const f16x8*)(ap + rd[kk]);
            acc0 = __builtin_amdgcn_mfma_f32_16x16x32_f16(af, bfrag[0][kk], acc0, 0, 0, 0);
            acc1 = __builtin_amdgcn_mfma_f32_16x16x32_f16(af, bfrag[1][kk], acc1, 0, 0, 0);
            acc2 = __builtin_amdgcn_mfma_f32_16x16x32_f16(af, bfrag[2][kk], acc2, 0, 0, 0);
            acc3 = __builtin_amdgcn_mfma_f32_16x16x32_f16(af, bfrag[3][kk], acc3, 0, 0, 0);
        }
        __builtin_amdgcn_s_setprio(0);
        #pragma unroll
        for (int r = 0; r < 4; ++r) {
            ssum[0] += acc0[r] * acc0[r];
            ssum[1] += acc1[r] * acc1[r];
            ssum[2] += acc2[r] * acc2[r];
            ssum[3] += acc3[r] * acc3[r];
        }

        if (mt < NT2 - 1) {
            // fold+write tile mt+1 (loads issued one iteration ago)
            char* wp = lds + (((mt + 1) & 1) << 14);
            const bool valid = (mt != NT2 - 2) || (sw2 == 0);  // tile 8: only window 256
            fold_write(wp, valid);
            if (mt < NT2 - 2) {   // issue loads for tile mt+2; in flight across barrier
                const uint tb = (uint)((mt + 2) * WT2 * HOP * 4);
                fva = load4u(xrow + min(voff_f + tb,      vclamp));
                fvb = load4u(xrow + min(voff_f + tb + 16, vclamp));
                rva = load4u(xrow + min(voff_r + tb,      vclamp));
                rvb = load4u(xrow + min(voff_r + tb + 16, vclamp));
            }
            asm volatile("s_waitcnt lgkmcnt(0)" ::: "memory");  // drain ds ops only
            __builtin_amdgcn_s_barrier();
            asm volatile("" ::: "memory");
        }
    }

    // ---- reduce over k-groups (D col = lane&15); scol[mg][comp] ----
    #pragma unroll
    for (int nt = 0; nt < 4; ++nt) {
        float v = ssum[nt];
        v += __shfl_xor(v, 16, 64);
        v += __shfl_xor(v, 32, 64);
        if (kg == 0) scol[mg][hs * 128 + ng * 64 + nt * 16 + r16] = v;
    }
    __syncthreads();
    if (tid < NB) {
        const float s = scol[0][tid] + scol[0][tid + NB]
                      + scol[1][tid] + scol[1][tid + NB];
        out[(size_t)row * NB + tid] = s * (1.0f / 257.0f);
    }
}

extern "C" void kernel_launch(void* const* d_in, const int* in_sizes, int n_in,
                              void* d_out, int out_size, void* d_ws, size_t ws_size,
                              hipStream_t stream) {
    const float* X = (const float*)d_in[0];
    float* out = (float*)d_out;
    f16* bt = (f16*)d_ws;   // 64 KB basis table
    (void)in_sizes; (void)n_in; (void)ws_size; (void)out_size;
    basis_kernel<<<dim3(16), dim3(256), 0, stream>>>(bt);
    psd_kernel<<<dim3(NROWS), dim3(512), 0, stream>>>(X, bt, out);
}

// Round 10
// 53.522 us; speedup vs baseline: 2.3626x; 2.3626x over previous
//
#include <hip/hip_runtime.h>
#include <hip/hip_bf16.h>

#define NS     32768
#define NROWS  2048
#define HOP    127
#define NW     257
#define NB     128
#define WTILE  16
#define NT     17            // sub-tiles of 16 windows; sub-tile 16 has 1 valid window
#define TWOPI_255 0.02463994236f   // 2*pi/255

typedef _Float16 f16;
typedef __attribute__((ext_vector_type(2))) _Float16 f16x2;
typedef __attribute__((ext_vector_type(4))) _Float16 f16x4;
typedef __attribute__((ext_vector_type(8))) _Float16 f16x8;
typedef __attribute__((ext_vector_type(4))) float f32x4;

__device__ inline f32x4 load4u(const char* p) {  // 4B-aligned 16B load
    f32x4 v;
    __builtin_memcpy(&v, p, 16);
    return v;
}

// ---------------------------------------------------------------------------
// Kernel 1: folded-DFT basis table (64 KB) in fragment order (as round 8).
// ---------------------------------------------------------------------------
__global__ __launch_bounds__(256)
void basis_kernel(f16* __restrict__ bt) {
    const int t  = blockIdx.x * 256 + threadIdx.x;   // 0..4095
    const int fi = t >> 6;
    const int l  = t & 63;
    const int cq = fi >> 3;
    const int nt = (fi >> 2) & 1;
    const int kk = fi & 3;
    const int is_sin = cq >> 2;
    const int f  = (cq & 3) * 32 + nt * 16 + (l & 15);   // freq 0..127
    int m = (f * (kk * 32 + (l >> 4) * 8)) % 255;
    f16x8 v;
    #pragma unroll
    for (int j = 0; j < 8; ++j) {
        const float ang = (float)m * TWOPI_255;
        v[j] = (f16)(is_sin ? __sinf(ang) : __cosf(ang));
        m += f; if (m >= 255) m -= 255;
    }
    *(f16x8*)(bt + (size_t)t * 8) = v;   // 16B/thread, coalesced
}

// ---------------------------------------------------------------------------
// Kernel 2: one block (8 waves, 512 thr) per row; wave cq owns 32 comps
// (bfrag = 32 VGPR -- hard constraint for (512,6) occupancy).
// QUAD-buffered 16-window sub-tiles, barrier every OTHER sub-tile (9 total).
// Hazards: buf b reused 4 sub-tiles apart; every write->read and read->write
// window spans >=1 of the odd-iteration barriers.
// K folded 255->128: y+[k]=x[k]+x[255-k] (cos), y-[k]=x[k]-x[255-k] (sin).
// S[f] = (sum_w Ccos^2 + Csin^2)/257.
// ---------------------------------------------------------------------------
__global__ __launch_bounds__(512, 6)
void psd_kernel(const float* __restrict__ X, const f16* __restrict__ bt,
                float* __restrict__ out) {
    const int row  = blockIdx.x;
    const int tid  = threadIdx.x;
    const int lane = tid & 63;
    const int cq   = tid >> 6;      // wave 0..7
    const int r16  = lane & 15;
    const int kg   = lane >> 4;
    const int is_sin = cq >> 2;     // waves 4..7 -> sin half

    __shared__ alignas(16) f16 atile[4][WTILE * 256];  // 4 x 8 KB, XOR-swizzled
    __shared__ float scol[256];

    const char* __restrict__ xrow = (const char*)(X + (size_t)row * NS);

    const int sw  = tid >> 5;           // staging window 0..15
    const int sq  = tid & 31;           // staging k-quad 0..31

    // loop-invariant per-lane global byte offsets (tile-local)
    const uint voff_f = (uint)((sw * HOP + sq * 4) * 4);
    const uint voff_r = (uint)((sw * HOP + 252 - sq * 4) * 4);
    const uint vclamp = (uint)((NS - 4) * 4);

    // ---- sub-tile-0 staging loads ----
    f32x4 fv = load4u(xrow + voff_f);
    f32x4 rv = load4u(xrow + voff_r);

    // ---- basis fragments: 8 coalesced dwordx4 (table L2-resident) ----
    f16x8 bfrag[2][4];
    {
        const char* bp = (const char*)bt + (uint)(cq * 8192 + lane * 16);
        #pragma unroll
        for (int nt = 0; nt < 2; ++nt)
            #pragma unroll
            for (int kk = 0; kk < 4; ++kk)
                bfrag[nt][kk] = *(const f16x8*)(bp + (uint)((nt * 4 + kk) * 1024));
    }

    char* const lds = (char*)&atile[0][0];

    // hoisted LDS byte offsets
    const uint swz  = (uint)((sw & 7) << 4);
    const uint wr_p = ((uint)(sw * 512 + sq * 8)) ^ swz;         // y+ (8B)
    const uint wr_m = ((uint)(sw * 512 + sq * 8 + 256)) ^ swz;   // y- (8B)
    const uint rswz = (uint)((r16 & 7) << 4);
    uint rd[4];
    #pragma unroll
    for (int kk = 0; kk < 4; ++kk)
        rd[kk] = ((uint)(r16 * 512 + is_sin * 256 + kg * 16 + kk * 64)) ^ rswz;

    // ---- packed fold (4 pairs) + 2 x ds_write_b64 ----
    auto fold_write = [&](char* wp, bool valid) {
        // partner of k=sq*4+j is rv[3-j]
        const f16x2 fp01 = __builtin_bit_cast(f16x2, __builtin_amdgcn_cvt_pkrtz(fv[0], fv[1]));
        const f16x2 fp23 = __builtin_bit_cast(f16x2, __builtin_amdgcn_cvt_pkrtz(fv[2], fv[3]));
        const f16x2 rp01 = __builtin_bit_cast(f16x2, __builtin_amdgcn_cvt_pkrtz(rv[3], rv[2]));
        const f16x2 rp23 = __builtin_bit_cast(f16x2, __builtin_amdgcn_cvt_pkrtz(rv[1], rv[0]));
        const f16x2 yp01 = fp01 + rp01, yp23 = fp23 + rp23;
        const f16x2 ym01 = fp01 - rp01, ym23 = fp23 - rp23;
        f16x4 h0, h1;
        h0[0] = yp01[0]; h0[1] = yp01[1]; h0[2] = yp23[0]; h0[3] = yp23[1];
        h1[0] = ym01[0]; h1[1] = ym01[1]; h1[2] = ym23[0]; h1[3] = ym23[1];
        if (sq == 0) { h0[0] = (f16)fv[0]; h1[0] = (f16)0.0f; }  // k=0: pad partner
        if (!valid) {
            #pragma unroll
            for (int j = 0; j < 4; ++j) { h0[j] = (f16)0.0f; h1[j] = (f16)0.0f; }
        }
        *(f16x4*)(wp + wr_p) = h0;
        *(f16x4*)(wp + wr_m) = h1;
    };

    // ---- prologue: fold st0, st1; issue st2 loads; one barrier ----
    fold_write(lds + (0 << 13), true);
    {
        const uint tb = (uint)(1 * WTILE * HOP * 4);
        fv = load4u(xrow + (voff_f + tb));
        rv = load4u(xrow + (voff_r + tb));
    }
    fold_write(lds + (1 << 13), true);
    {
        const uint tb = (uint)(2 * WTILE * HOP * 4);
        fv = load4u(xrow + (voff_f + tb));
        rv = load4u(xrow + (voff_r + tb));
    }
    asm volatile("s_waitcnt lgkmcnt(0)" ::: "memory");
    __builtin_amdgcn_s_barrier();
    asm volatile("" ::: "memory");

    float ssum0 = 0.f, ssum1 = 0.f;

    // iter mt: MFMA st=mt from buf[mt&3]; fold st=mt+2 -> buf[(mt+2)&3];
    // issue loads st=mt+3; barrier after odd iters only.
    for (int mt = 0; mt < NT; ++mt) {
        const char* ap = lds + ((mt & 3) << 13);

        f32x4 acc0 = {0,0,0,0}, acc1 = {0,0,0,0};
        __builtin_amdgcn_s_setprio(1);
        #pragma unroll
        for (int kk = 0; kk < 4; ++kk) {
            const f16x8 af = *(const f16x8*)(ap + rd[kk]);
            acc0 = __builtin_amdgcn_mfma_f32_16x16x32_f16(af, bfrag[0][kk], acc0, 0, 0, 0);
            acc1 = __builtin_amdgcn_mfma_f32_16x16x32_f16(af, bfrag[1][kk], acc1, 0, 0, 0);
        }
        __builtin_amdgcn_s_setprio(0);
        #pragma unroll
        for (int r = 0; r < 4; ++r) {
            ssum0 += acc0[r] * acc0[r];
            ssum1 += acc1[r] * acc1[r];
        }

        if (mt + 2 < NT) {
            // fold+write sub-tile mt+2 (loads issued one iteration ago)
            char* wp = lds + (((mt + 2) & 3) << 13);
            const bool valid = (mt + 2 != 16) || (sw == 0);  // st16: only window 256
            fold_write(wp, valid);
            if (mt + 3 < NT) {   // issue loads for st=mt+3; in flight across barrier
                const uint tb = (uint)((mt + 3) * WTILE * HOP * 4);
                fv = load4u(xrow + min(voff_f + tb, vclamp));
                rv = load4u(xrow + min(voff_r + tb, vclamp));
            }
        }
        if (mt & 1) {
            asm volatile("s_waitcnt lgkmcnt(0)" ::: "memory");  // drain ds ops only
            __builtin_amdgcn_s_barrier();
            asm volatile("" ::: "memory");
        }
    }

    // ---- reduce over k-groups (D col = lane&15); one owner wave per comp ----
    {
        float v = ssum0;
        v += __shfl_xor(v, 16, 64);
        v += __shfl_xor(v, 32, 64);
        if (kg == 0) scol[is_sin * 128 + (cq & 3) * 32 + r16] = v;
        float w = ssum1;
        w += __shfl_xor(w, 16, 64);
        w += __shfl_xor(w, 32, 64);
        if (kg == 0) scol[is_sin * 128 + (cq & 3) * 32 + 16 + r16] = w;
    }
    __syncthreads();
    if (tid < NB) {
        out[(size_t)row * NB + tid] = (scol[tid] + scol[tid + NB]) * (1.0f / 257.0f);
    }
}

extern "C" void kernel_launch(void* const* d_in, const int* in_sizes, int n_in,
                              void* d_out, int out_size, void* d_ws, size_t ws_size,
                              hipStream_t stream) {
    const float* X = (const float*)d_in[0];
    float* out = (float*)d_out;
    f16* bt = (f16*)d_ws;   // 64 KB basis table
    (void)in_sizes; (void)n_in; (void)ws_size; (void)out_size;
    basis_kernel<<<dim3(16), dim3(256), 0, stream>>>(bt);
    psd_kernel<<<dim3(NROWS), dim3(512), 0, stream>>>(X, bt, out);
}